// Round 2
// baseline (753.899 us; speedup 1.0000x reference)
//
#include <hip/hip_runtime.h>

// Segment mean: x [N=1048576, D=128] fp32, B=16 contiguous segments (lengths[16]).
// out [16,128] fp32 per-segment column means.
//
// Balanced design (R2): N/512 = 2048 blocks, each owns EXACTLY 512 contiguous
// rows (64 iterations of 8 rows x 256 threads, no tail, no imbalance --
// previous per-segment partition made runtime = slowest segment, ~1.5x mean).
// A 512-row chunk crosses at most one segment boundary (min seg ~32k rows):
// keep accT (all rows) and accL (rows < boundary, predicated); hi = T - L.
// Each block writes two tagged 512B partials to d_ws. Phase 2 (16x128) sums
// tagged slots in the block-range covering segment s, divides by lengths[s].
// Deterministic, no atomics.

#define SEG_D 128
#define NSEG 16
#define RPB 512   // rows per block (N = 2048 * 512 exactly)

__global__ __launch_bounds__(256) void seg_partial_bal(
    const float* __restrict__ x,
    const int* __restrict__ lengths,
    float* __restrict__ partial,   // [2*gridDim.x][128]
    int* __restrict__ tags) {      // [2*gridDim.x]
  const int b  = blockIdx.x;
  const int r0 = b * RPB;

  // Find segment containing r0 and its end row (uniform scalar work).
  int cum = 0, seg_lo = 0, boundary = 0;
  for (int i = 0; i < NSEG; ++i) {
    const int l = lengths[i];
    if (cum <= r0) { seg_lo = i; boundary = cum + l; }
    cum += l;
  }

  const int ro = threadIdx.x >> 5;         // row slot 0..7
  const int cg = (threadIdx.x & 31) << 2;  // float column within row

  const float* p = x + (long)(r0 + ro) * SEG_D + cg;
  int r = r0 + ro;

  float4 accT = make_float4(0.f, 0.f, 0.f, 0.f);
  float4 accL = make_float4(0.f, 0.f, 0.f, 0.f);

#pragma unroll 4
  for (int i = 0; i < RPB / 8; ++i) {
    const float4 v = *(const float4*)p;
    p += 8 * SEG_D;
    const bool lo = (r < boundary);
    r += 8;
    accT.x += v.x; accT.y += v.y; accT.z += v.z; accT.w += v.w;
    accL.x += lo ? v.x : 0.f;
    accL.y += lo ? v.y : 0.f;
    accL.z += lo ? v.z : 0.f;
    accL.w += lo ? v.w : 0.f;
  }

  const float4 accH = make_float4(accT.x - accL.x, accT.y - accL.y,
                                  accT.z - accL.z, accT.w - accL.w);

  __shared__ float4 redL[256];
  __shared__ float4 redH[256];
  redL[threadIdx.x] = accL;
  redH[threadIdx.x] = accH;
  __syncthreads();
  if (threadIdx.x < 32) {
    float4 sL = redL[threadIdx.x];
    float4 sH = redH[threadIdx.x];
#pragma unroll
    for (int i = 1; i < 8; ++i) {
      const float4 vL = redL[threadIdx.x + i * 32];
      const float4 vH = redH[threadIdx.x + i * 32];
      sL.x += vL.x; sL.y += vL.y; sL.z += vL.z; sL.w += vL.w;
      sH.x += vH.x; sH.y += vH.y; sH.z += vH.z; sH.w += vH.w;
    }
    *(float4*)(partial + (long)(2 * b) * SEG_D + cg)     = sL;
    *(float4*)(partial + (long)(2 * b + 1) * SEG_D + cg) = sH;
  }
  if (threadIdx.x == 0) {
    tags[2 * b]     = seg_lo;
    tags[2 * b + 1] = (seg_lo + 1 < NSEG) ? seg_lo + 1 : NSEG - 1;
  }
}

__global__ __launch_bounds__(SEG_D) void seg_finish_bal(
    const float* __restrict__ partial,
    const int* __restrict__ tags,
    const int* __restrict__ lengths,
    float* __restrict__ out) {
  const int s = blockIdx.x;
  const int d = threadIdx.x;

  int cum = 0, start_s = 0, len_s = 1;
  for (int i = 0; i < NSEG; ++i) {
    const int l = lengths[i];
    if (i == s) { start_s = cum; len_s = l; }
    cum += l;
  }

  // Blocks whose chunks intersect segment s.
  const int b_first = start_s / RPB;
  const int b_last  = (start_s + len_s - 1) / RPB;

  float sum = 0.f;
  for (int slot = 2 * b_first; slot <= 2 * b_last + 1; ++slot) {
    if (tags[slot] == s) sum += partial[(long)slot * SEG_D + d];
  }
  out[s * SEG_D + d] = sum / (float)len_s;
}

extern "C" void kernel_launch(void* const* d_in, const int* in_sizes, int n_in,
                              void* d_out, int out_size, void* d_ws, size_t ws_size,
                              hipStream_t stream) {
  const float* x       = (const float*)d_in[0];
  // d_in[1] = segment_ids (unused: segments are contiguous, lengths suffice).
  const int*   lengths = (const int*)d_in[2];
  float*       out     = (float*)d_out;

  const int n_rows = in_sizes[0] / SEG_D;   // 1048576
  const int nb     = n_rows / RPB;          // 2048 (exact for this problem)

  float* partial = (float*)d_ws;                              // 2*nb*128 floats = 2 MB
  int*   tags    = (int*)((char*)d_ws + (size_t)2 * nb * SEG_D * sizeof(float));

  seg_partial_bal<<<nb, 256, 0, stream>>>(x, lengths, partial, tags);
  seg_finish_bal<<<NSEG, SEG_D, 0, stream>>>(partial, tags, lengths, out);
}

// Round 3
// 739.332 us; speedup vs baseline: 1.0197x; 1.0197x over previous
//
#include <hip/hip_runtime.h>

// Segment mean: x [N=1048576, D=128] fp32, B=16 contiguous segments (lengths[16]).
// out [16,128] fp32 per-segment column means.
//
// Phase 1 (balanced): nb = N/512 = 2048 blocks, each owns EXACTLY 512
// contiguous rows (64 iters x 8 rows x 256 thr; no tail, no imbalance).
// A 512-row chunk crosses at most one segment boundary (min seg len ~32k):
// accT = all rows, accL = rows below boundary (predicated), accH = T - L.
// Block b writes slot 2b (lo partial) and 2b+1 (hi partial) to d_ws.
// Slot->segment mapping is implied by lengths: slot 2b belongs to
// seg(b*512), slot 2b+1 to seg(b*512)+1 -- no tags array needed.
//
// Phase 2: 16 blocks x 256 threads. Threads 0..127 (j=0) sum lo-slots of
// blocks starting inside segment s; threads 128..255 (j=1) sum hi-slots of
// blocks starting inside segment s-1 (their above-boundary rows are s's).
// Branch-free block ranges from the lengths prefix sum; LDS combine; divide.
// Deterministic, no atomics.

#define SEG_D 128
#define NSEG 16
#define RPB 512   // rows per block (N = 2048 * 512 exactly)

__global__ __launch_bounds__(256) void seg_partial_bal(
    const float* __restrict__ x,
    const int* __restrict__ lengths,
    float* __restrict__ partial) {   // [2*gridDim.x][128]
  const int b  = blockIdx.x;
  const int r0 = b * RPB;

  // boundary = end row of the segment containing r0 (uniform scalar work).
  int cum = 0, boundary = 0;
  for (int i = 0; i < NSEG; ++i) {
    const int l = lengths[i];
    if (cum <= r0) boundary = cum + l;
    cum += l;
  }

  const int ro = threadIdx.x >> 5;         // row slot 0..7
  const int cg = (threadIdx.x & 31) << 2;  // float column within row

  const float* p = x + (long)(r0 + ro) * SEG_D + cg;
  int r = r0 + ro;

  float4 accT = make_float4(0.f, 0.f, 0.f, 0.f);
  float4 accL = make_float4(0.f, 0.f, 0.f, 0.f);

#pragma unroll 8
  for (int i = 0; i < RPB / 8; ++i) {
    const float4 v = *(const float4*)p;
    p += 8 * SEG_D;
    const bool lo = (r < boundary);
    r += 8;
    accT.x += v.x; accT.y += v.y; accT.z += v.z; accT.w += v.w;
    accL.x += lo ? v.x : 0.f;
    accL.y += lo ? v.y : 0.f;
    accL.z += lo ? v.z : 0.f;
    accL.w += lo ? v.w : 0.f;
  }

  const float4 accH = make_float4(accT.x - accL.x, accT.y - accL.y,
                                  accT.z - accL.z, accT.w - accL.w);

  __shared__ float4 redL[256];
  __shared__ float4 redH[256];
  redL[threadIdx.x] = accL;
  redH[threadIdx.x] = accH;
  __syncthreads();
  if (threadIdx.x < 32) {
    float4 sL = redL[threadIdx.x];
    float4 sH = redH[threadIdx.x];
#pragma unroll
    for (int i = 1; i < 8; ++i) {
      const float4 vL = redL[threadIdx.x + i * 32];
      const float4 vH = redH[threadIdx.x + i * 32];
      sL.x += vL.x; sL.y += vL.y; sL.z += vL.z; sL.w += vL.w;
      sH.x += vH.x; sH.y += vH.y; sH.z += vH.z; sH.w += vH.w;
    }
    *(float4*)(partial + (long)(2 * b) * SEG_D + cg)     = sL;
    *(float4*)(partial + (long)(2 * b + 1) * SEG_D + cg) = sH;
  }
}

__global__ __launch_bounds__(256) void seg_finish_bal(
    const float* __restrict__ partial,
    const int* __restrict__ lengths,
    float* __restrict__ out) {
  __shared__ int starts[NSEG + 1];
  if (threadIdx.x == 0) {
    int c = 0;
    for (int i = 0; i < NSEG; ++i) { starts[i] = c; c += lengths[i]; }
    starts[NSEG] = c;
  }
  __syncthreads();

  const int s = blockIdx.x;
  const int d = threadIdx.x & 127;
  const int j = threadIdx.x >> 7;   // 0: lo slots of seg s; 1: hi slots of seg s-1
  const int t = s - j;              // source segment whose chunks we scan

  float sum = 0.f;
  if (t >= 0) {
    // blocks b whose chunk STARTS inside segment t: starts[t] <= b*RPB < starts[t+1]
    const int bA = (starts[t] + RPB - 1) / RPB;
    const int bB = (starts[t + 1] + RPB - 1) / RPB - 1;
    const float* p = partial + ((long)2 * bA + j) * SEG_D + d;
    for (int b = bA; b <= bB; ++b) {
      sum += *p;
      p += 2 * SEG_D;
    }
  }

  __shared__ float red[256];
  red[threadIdx.x] = sum;
  __syncthreads();
  if (threadIdx.x < 128) {
    out[s * SEG_D + d] = (red[d] + red[d + 128]) / (float)lengths[s];
  }
}

extern "C" void kernel_launch(void* const* d_in, const int* in_sizes, int n_in,
                              void* d_out, int out_size, void* d_ws, size_t ws_size,
                              hipStream_t stream) {
  const float* x       = (const float*)d_in[0];
  // d_in[1] = segment_ids (unused: segments are contiguous, lengths suffice).
  const int*   lengths = (const int*)d_in[2];
  float*       out     = (float*)d_out;

  const int n_rows = in_sizes[0] / SEG_D;   // 1048576
  const int nb     = n_rows / RPB;          // 2048 (exact: N = 2048*512)

  float* partial = (float*)d_ws;            // 2*nb*128 floats = 2 MB

  seg_partial_bal<<<nb, 256, 0, stream>>>(x, lengths, partial);
  seg_finish_bal<<<NSEG, 256, 0, stream>>>(partial, lengths, out);
}